// Round 6
// baseline (2814.130 us; speedup 1.0000x reference)
//
#include <hip/hip_runtime.h>
#include <hip/hip_bf16.h>
#include <math.h>

using u16 = unsigned short;
typedef __attribute__((ext_vector_type(8))) short short8;
typedef __attribute__((ext_vector_type(8))) _Float16 half8;
typedef __attribute__((ext_vector_type(4))) float f32x4;
typedef __attribute__((ext_vector_type(4))) u16 u16x4;

__device__ __constant__ int c_OFF[9] = {0, 119, 123, 135, 147, 157, 163, 169, 171};

__device__ __forceinline__ float h2f(u16 u) {
    _Float16 h;
    __builtin_memcpy(&h, &u, 2);
    return (float)h;
}
__device__ __forceinline__ u16 f2h(float f) {
    _Float16 h = (_Float16)f;
    u16 u;
    __builtin_memcpy(&u, &h, 2);
    return u;
}
__device__ __forceinline__ float sigf(float x) { return 1.f / (1.f + expf(-x)); }

// ---------------- diagnostics ----------------
__global__ void k_diagf(float* out, int G, float val) {
    int i = blockIdx.x * 256 + threadIdx.x;
    if (i < G) out[i] = val;
}

// ---------------- zero helpers ----------------
__global__ void k_zero_f32(float* p, int n) {
    int i = blockIdx.x * 256 + threadIdx.x;
    if (i < n) p[i] = 0.f;
}
__global__ void k_zero_u16(u16* p, int n) {
    int i = blockIdx.x * 256 + threadIdx.x;
    if (i < n) p[i] = 0;
}
__global__ void k_zero_int(int* p, int n) {
    int i = blockIdx.x * 256 + threadIdx.x;
    if (i < n) p[i] = 0;
}

// ---------------- fp32 -> fp16 convert ----------------
__global__ void k_cvtW(const float* __restrict__ src, u16* __restrict__ dst, int n) {
    int i = blockIdx.x * 256 + threadIdx.x;
    if (i < n) dst[i] = f2h(src[i]);
}

// ---------------- atom encoder: sum 9 fp32 embedding rows -> fp16 X ----------------
__global__ void k_embed(const int* __restrict__ x, const float* __restrict__ emb,
                        u16* __restrict__ out, int N) {
    __shared__ int rows[9];
    int n = blockIdx.x;
    int d = threadIdx.x;
    if (d < 9) rows[d] = x[n * 9 + d] + c_OFF[d];
    __syncthreads();
    float s = 0.f;
#pragma unroll
    for (int c = 0; c < 9; ++c) s += emb[rows[c] * 256 + d];
    out[(size_t)n * 256 + d] = f2h(s);
}

// ---------------- CSR build (in-place in rp) ----------------
__global__ void k_count(const int* __restrict__ tgt, int* rp, int E) {
    int e = blockIdx.x * 256 + threadIdx.x;
    if (e < E) atomicAdd(&rp[tgt[e]], 1);
}

__global__ void k_scan1(int* __restrict__ rp, int* __restrict__ bsum, int N) {
    int t = threadIdx.x;
    int base = blockIdx.x * 1024 + t * 4;
    int v0 = 0, v1 = 0, v2 = 0, v3 = 0;
    if (base + 3 < N) {
        v0 = rp[base]; v1 = rp[base + 1]; v2 = rp[base + 2]; v3 = rp[base + 3];
    } else {
        if (base < N) v0 = rp[base];
        if (base + 1 < N) v1 = rp[base + 1];
        if (base + 2 < N) v2 = rp[base + 2];
    }
    int s = v0 + v1 + v2 + v3;
    int lane = t & 63, w = t >> 6;
    int x = s;
    for (int o = 1; o < 64; o <<= 1) {
        int y = __shfl_up(x, o, 64);
        if (lane >= o) x += y;
    }
    __shared__ int wsum[4];
    if (lane == 63) wsum[w] = x;
    __syncthreads();
    int woff = 0;
    for (int i = 0; i < w; ++i) woff += wsum[i];
    int excl = woff + x - s;
    if (base < N) rp[base] = excl;
    if (base + 1 < N) rp[base + 1] = excl + v0;
    if (base + 2 < N) rp[base + 2] = excl + v0 + v1;
    if (base + 3 < N) rp[base + 3] = excl + v0 + v1 + v2;
    if (t == 255) bsum[blockIdx.x] = wsum[0] + wsum[1] + wsum[2] + wsum[3];
}

__global__ void k_scan2(int* bsum, int nb) {
    int t = threadIdx.x;
    int s = (t < nb) ? bsum[t] : 0;
    int lane = t & 63, w = t >> 6;
    int x = s;
    for (int o = 1; o < 64; o <<= 1) {
        int y = __shfl_up(x, o, 64);
        if (lane >= o) x += y;
    }
    __shared__ int wsum[4];
    if (lane == 63) wsum[w] = x;
    __syncthreads();
    int woff = 0;
    for (int i = 0; i < w; ++i) woff += wsum[i];
    if (t < nb) bsum[t] = woff + x - s;
}

__global__ void k_scan3(int* __restrict__ rp, const int* __restrict__ bsum, int N) {
    int i = blockIdx.x * 256 + threadIdx.x;
    if (i < N) rp[i] += bsum[i >> 10];
}

// fill using rp as running cursors; afterwards rp[n] = end(n), start(n) = rp[n-1]
__global__ void k_fill(const int* __restrict__ src, const int* __restrict__ tgt,
                       int* __restrict__ rp, int* __restrict__ esrc, int E) {
    int e = blockIdx.x * 256 + threadIdx.x;
    if (e < E) {
        int t = tgt[e];
        int p = atomicAdd(&rp[t], 1);
        esrc[p] = src[e];
    }
}

// ---------------- in-place GEMM: X[64 rows] <- X[64 rows] @ Wp^T (+cvec), fp16 MFMA ----------------
__global__ __launch_bounds__(256, 2) void k_gemm_ip(u16* __restrict__ X,
                                                    const u16* __restrict__ W,
                                                    const float* __restrict__ cvec, int N) {
    __shared__ u16 As[64][264];
    __shared__ u16 Ws[256][40];
    int r0 = blockIdx.x * 64;
    int tid = threadIdx.x, lane = tid & 63, w = tid >> 6;
#pragma unroll
    for (int i = 0; i < 8; ++i) {
        int chunk = i * 256 + tid;
        int r = chunk >> 5, c8 = chunk & 31;
        *(short8*)&As[r][c8 * 8] = *(const short8*)&X[(size_t)(r0 + r) * 256 + c8 * 8];
    }
    f32x4 acc[16];
#pragma unroll
    for (int o = 0; o < 16; ++o) acc[o] = f32x4{0.f, 0.f, 0.f, 0.f};
    for (int k0 = 0; k0 < 256; k0 += 32) {
        __syncthreads();  // covers As staging (iter 0) and prior Ws readers
#pragma unroll
        for (int i = 0; i < 4; ++i) {
            int chunk = i * 256 + tid;
            int r = chunk >> 2, c8 = chunk & 3;
            *(short8*)&Ws[r][c8 * 8] = *(const short8*)&W[(size_t)r * 256 + k0 + c8 * 8];
        }
        __syncthreads();
        half8 af = *(const half8*)&As[w * 16 + (lane & 15)][k0 + (lane >> 4) * 8];
#pragma unroll
        for (int o = 0; o < 16; ++o) {
            half8 wf = *(const half8*)&Ws[o * 16 + (lane & 15)][(lane >> 4) * 8];
            acc[o] = __builtin_amdgcn_mfma_f32_16x16x32_f16(af, wf, acc[o], 0, 0, 0);
        }
    }
#pragma unroll
    for (int o = 0; o < 16; ++o) {
        int col = o * 16 + (lane & 15);
        float cv = cvec ? cvec[col] : 0.f;
#pragma unroll
        for (int r = 0; r < 4; ++r) {
            int row = r0 + w * 16 + (lane >> 4) * 4 + r;
            X[(size_t)row * 256 + col] = f2h(acc[o][r] + cv);
        }
    }
}

// ---------------- snapshot a 64-column slice ----------------
__global__ void k_copycol(const u16* __restrict__ X, u16* __restrict__ Q, int q, int N) {
    int i = blockIdx.x * 256 + threadIdx.x;
    if (i >= N * 16) return;
    int n = i >> 4, c4 = (i & 15) * 4;
    *(u16x4*)&Q[(size_t)n * 64 + c4] = *(const u16x4*)&X[(size_t)n * 256 + q * 64 + c4];
}

// ---------------- aggregation on a 64-col quarter, in place into X ----------------
template <bool RS>
__global__ __launch_bounds__(256) void k_aggq(const u16* __restrict__ Q,
                                              const int* __restrict__ rp,
                                              const int* __restrict__ esrc,
                                              const float* __restrict__ bias,
                                              u16* __restrict__ X,
                                              float* __restrict__ stats, int q, int N) {
    int lane = threadIdx.x & 63;
    int gw = blockIdx.x * 4 + (threadIdx.x >> 6);
    int nw = gridDim.x * 4;
    int col = q * 64 + lane;
    float bv = bias[col];
    float ss = 0.f, qq = 0.f;
    for (int n = gw; n < N; n += nw) {
        int end = rp[n];
        int start = n ? rp[n - 1] : 0;
        float dn = rsqrtf((float)(end - start) + 1.f);
        float a = h2f(Q[(size_t)n * 64 + lane]) * dn * dn + bv;
        for (int j = start; j < end; ++j) {
            int s = esrc[j];
            int e2 = rp[s];
            int s2 = s ? rp[s - 1] : 0;
            float ds = rsqrtf((float)(e2 - s2) + 1.f);
            a += h2f(Q[(size_t)s * 64 + lane]) * ds * dn;
        }
        if (RS) {
            a = fmaxf(a, 0.f);
            ss += a;
            qq += a * a;
        }
        X[(size_t)n * 256 + col] = f2h(a);
    }
    if (RS) {
        __shared__ float sh[128];
        int t = threadIdx.x;
        if (t < 128) sh[t] = 0.f;
        __syncthreads();
        atomicAdd(&sh[lane], ss);
        atomicAdd(&sh[64 + lane], qq);
        __syncthreads();
        if (t < 64) {
            atomicAdd(&stats[col], sh[lane]);
            atomicAdd(&stats[256 + col], sh[64 + lane]);
        }
    }
}

__global__ void k_bnparam(const float* __restrict__ stats, const float* __restrict__ gamma,
                          const float* __restrict__ beta, float* __restrict__ st, int N) {
    int d = threadIdx.x;
    float inv = 1.f / (float)N;
    float mu = stats[d] * inv;
    float var = fmaxf(stats[256 + d] * inv - mu * mu, 0.f);
    float sc = gamma[d] * rsqrtf(var + 1e-5f);
    st[d] = sc;
    st[256 + d] = beta[d] - mu * sc;
}

// fold bn into next conv's weights: Wp = W * s[col] (fp16), cvec[o] = sum_k t[k]*W[o][k]
__global__ void k_fold(const float* __restrict__ W, const float* __restrict__ st,
                       u16* __restrict__ Wp, float* __restrict__ cvec) {
    __shared__ float red[256];
    int o = blockIdx.x, k = threadIdx.x;
    float w = W[o * 256 + k];
    Wp[o * 256 + k] = f2h(w * st[k]);
    red[k] = w * st[256 + k];
    __syncthreads();
    for (int s = 128; s > 0; s >>= 1) {
        if (k < s) red[k] += red[k + s];
        __syncthreads();
    }
    if (k == 0) cvec[o] = red[0];
}

// ---------------- set2set GEMM: C[M,O](f32) = A[M,K](fp16) @ W[O,K](fp16)^T + cvec ----------------
__global__ __launch_bounds__(256, 2) void k_gemmf(const u16* __restrict__ A,
                                                  const u16* __restrict__ W,
                                                  const float* __restrict__ cvec,
                                                  float* __restrict__ C, int M, int K, int O) {
    const int PAD = 8;
    __shared__ u16 As[128][64 + PAD];
    __shared__ u16 Ws[128][64 + PAD];
    int tM = blockIdx.x, tO = blockIdx.y;
    int tid = threadIdx.x;
    int lane = tid & 63, wid = tid >> 6;
    int wM = wid & 1, wO = wid >> 1;
    f32x4 acc[4][4] = {};
    size_t rowA0 = (size_t)tM * 128, rowW0 = (size_t)tO * 128;
    for (int k0 = 0; k0 < K; k0 += 64) {
#pragma unroll
        for (int i = 0; i < 4; ++i) {
            int chunk = tid + i * 256;
            int r = chunk >> 3, c16 = chunk & 7;
            *(short8*)&As[r][c16 * 8] = *(const short8*)&A[(rowA0 + r) * K + k0 + c16 * 8];
            *(short8*)&Ws[r][c16 * 8] = *(const short8*)&W[(rowW0 + r) * K + k0 + c16 * 8];
        }
        __syncthreads();
#pragma unroll
        for (int ks = 0; ks < 2; ++ks) {
            half8 af[4], wf[4];
#pragma unroll
            for (int m = 0; m < 4; ++m)
                af[m] = *(const half8*)&As[wM * 64 + m * 16 + (lane & 15)][ks * 32 + (lane >> 4) * 8];
#pragma unroll
            for (int o = 0; o < 4; ++o)
                wf[o] = *(const half8*)&Ws[wO * 64 + o * 16 + (lane & 15)][ks * 32 + (lane >> 4) * 8];
#pragma unroll
            for (int m = 0; m < 4; ++m)
#pragma unroll
                for (int o = 0; o < 4; ++o)
                    acc[m][o] = __builtin_amdgcn_mfma_f32_16x16x32_f16(af[m], wf[o], acc[m][o], 0, 0, 0);
        }
        __syncthreads();
    }
#pragma unroll
    for (int m = 0; m < 4; ++m) {
        int R0 = tM * 128 + wM * 64 + m * 16 + (lane >> 4) * 4;
#pragma unroll
        for (int o = 0; o < 4; ++o) {
            int Cc = tO * 128 + wO * 64 + o * 16 + (lane & 15);
            float cv = cvec[Cc];
#pragma unroll
            for (int r = 0; r < 4; ++r)
                C[(size_t)(R0 + r) * O + Cc] = acc[m][o][r] + cv;
        }
    }
}

// ---------------- set2set pieces ----------------
__global__ void k_wcat(const float* __restrict__ Wi, const float* __restrict__ Wh,
                       const float* __restrict__ bi, const float* __restrict__ bh,
                       u16* __restrict__ Wcat, float* __restrict__ bcat) {
    int o = blockIdx.x;  // 1024
    int t = threadIdx.x;
    for (int c = t; c < 512; c += 256) Wcat[(size_t)o * 768 + c] = f2h(Wi[(size_t)o * 512 + c]);
    if (t < 256) Wcat[(size_t)o * 768 + 512 + t] = f2h(Wh[(size_t)o * 256 + t]);
    if (t == 0) bcat[o] = bi[o] + bh[o];
}

__global__ void k_lstm(const float* __restrict__ gates, float* __restrict__ cs,
                       float* __restrict__ hsb, u16* __restrict__ qsh, int G) {
    int idx = blockIdx.x * 256 + threadIdx.x;
    if (idx >= G * 256) return;
    int g = idx >> 8, d = idx & 255;
    const float* gt = &gates[(size_t)g * 1024];
    float gi = gt[d], gf = gt[256 + d], gg = gt[512 + d], go = gt[768 + d];
    float c = sigf(gf) * cs[idx] + sigf(gi) * tanhf(gg);
    float hh = sigf(go) * tanhf(c);
    cs[idx] = c;
    hsb[idx] = hh;
    u16 hb = f2h(hh);
    qsh[(size_t)g * 768 + d] = hb;        // q part of q_star
    qsh[(size_t)g * 768 + 512 + d] = hb;  // hs input to gates
}

__global__ __launch_bounds__(256) void k_attn(const u16* __restrict__ h3,
                                              const float* __restrict__ hs,
                                              const int* __restrict__ batch,
                                              u16* __restrict__ qsh, int N, int G) {
    int g = blockIdx.x;
    int tid = threadIdx.x, lane = tid & 63, wid = tid >> 6;
    int lo = 0, hi = N;
    while (lo < hi) {
        int mid = (lo + hi) >> 1;
        if (batch[mid] < g) lo = mid + 1; else hi = mid;
    }
    int start = lo;
    hi = N;
    while (lo < hi) {
        int mid = (lo + hi) >> 1;
        if (batch[mid] < g + 1) lo = mid + 1; else hi = mid;
    }
    int end = lo;
    int cnt = end - start;

    __shared__ float earr[512];
    __shared__ float red[256];

    float q0 = hs[(size_t)g * 256 + lane * 4 + 0];
    float q1 = hs[(size_t)g * 256 + lane * 4 + 1];
    float q2 = hs[(size_t)g * 256 + lane * 4 + 2];
    float q3 = hs[(size_t)g * 256 + lane * 4 + 3];

    float m = -INFINITY, z = 0.f, racc = 0.f;
    for (int c0 = start; c0 < end; c0 += 512) {
        int cn = min(512, end - c0);
        for (int i = wid; i < cn; i += 4) {
            u16x4 hv = *(const u16x4*)&h3[(size_t)(c0 + i) * 256 + lane * 4];
            float e = h2f(hv[0]) * q0 + h2f(hv[1]) * q1 + h2f(hv[2]) * q2 + h2f(hv[3]) * q3;
            for (int off = 32; off; off >>= 1) e += __shfl_xor(e, off, 64);
            if (lane == 0) earr[i] = e;
        }
        __syncthreads();
        float lm = -INFINITY;
        for (int i = tid; i < cn; i += 256) lm = fmaxf(lm, earr[i]);
        red[tid] = lm;
        __syncthreads();
        for (int s = 128; s > 0; s >>= 1) {
            if (tid < s) red[tid] = fmaxf(red[tid], red[tid + s]);
            __syncthreads();
        }
        float mnew = fmaxf(m, red[0]);
        __syncthreads();
        float rf = (m == -INFINITY) ? 0.f : expf(m - mnew);
        float lz = 0.f;
        for (int i = tid; i < cn; i += 256) {
            float ee = expf(earr[i] - mnew);
            earr[i] = ee;
            lz += ee;
        }
        red[tid] = lz;
        __syncthreads();
        for (int s = 128; s > 0; s >>= 1) {
            if (tid < s) red[tid] += red[tid + s];
            __syncthreads();
        }
        z = z * rf + red[0];
        __syncthreads();
        racc *= rf;
        for (int i = 0; i < cn; ++i)
            racc += earr[i] * h2f(h3[(size_t)(c0 + i) * 256 + tid]);
        m = mnew;
        __syncthreads();
    }
    float r = (cnt > 0) ? racc / fmaxf(z, 1e-30f) : 0.f;
    qsh[(size_t)g * 768 + 256 + tid] = f2h(r);
}

__global__ __launch_bounds__(128) void k_final(const u16* __restrict__ qsh,
                                               const float* __restrict__ l1W,
                                               const float* __restrict__ l1b,
                                               const float* __restrict__ l2W,
                                               const float* __restrict__ l2b,
                                               float* __restrict__ out, int G) {
    int g = blockIdx.x, t = threadIdx.x;
    __shared__ float qs[512];
    __shared__ float o1[128];
    for (int c = t; c < 512; c += 128) qs[c] = h2f(qsh[(size_t)g * 768 + c]);
    __syncthreads();
    float acc = l1b[t];
    const f32x4* wr = (const f32x4*)&l1W[(size_t)t * 512];
    for (int k = 0; k < 128; ++k) {
        f32x4 wv = wr[k];
#pragma unroll
        for (int j = 0; j < 4; ++j) acc += qs[k * 4 + j] * wv[j];
    }
    o1[t] = acc;
    __syncthreads();
    if (t < 64) {
        float s = o1[t] * l2W[t] + o1[t + 64] * l2W[t + 64];
        for (int off = 32; off; off >>= 1) s += __shfl_xor(s, off, 64);
        if (t == 0) out[g] = sigf(s + l2b[0]);
    }
}

// ---------------- host ----------------
extern "C" void kernel_launch(void* const* d_in, const int* in_sizes, int n_in,
                              void* d_out, int out_size, void* d_ws, size_t ws_size,
                              hipStream_t stream) {
    const int* x = (const int*)d_in[0];
    const int* ei = (const int*)d_in[1];
    const int* batch = (const int*)d_in[2];
    const float* atom_emb = (const float*)d_in[4];
    const float* W1 = (const float*)d_in[5];
    const float* b1 = (const float*)d_in[6];
    const float* W2 = (const float*)d_in[7];
    const float* b2 = (const float*)d_in[8];
    const float* W3 = (const float*)d_in[9];
    const float* b3 = (const float*)d_in[10];
    const float* gamma = (const float*)d_in[11];
    const float* beta = (const float*)d_in[12];
    const float* Wi = (const float*)d_in[13];
    const float* Wh = (const float*)d_in[14];
    const float* bi = (const float*)d_in[15];
    const float* bh = (const float*)d_in[16];
    const float* l1W = (const float*)d_in[17];
    const float* l1b = (const float*)d_in[18];
    const float* l2W = (const float*)d_in[19];
    const float* l2b = (const float*)d_in[20];

    const int N = in_sizes[0] / 9;
    const int E = in_sizes[1] / 2;
    const int G = out_size;
    const int* srcp = ei;
    const int* tgtp = ei + E;

    char* ws = (char*)d_ws;
    size_t off = 0;
    auto alloc = [&](size_t bytes) -> void* {
        void* p = ws + off;
        off += (bytes + 255) & ~(size_t)255;
        return p;
    };
    u16* X = (u16*)alloc((size_t)N * 256 * 2);  // 128 MiB, the only node buffer
    int* rp = (int*)alloc((size_t)N * 4);
    int* esrc = (int*)alloc((size_t)E * 4);
    float* stats = (float*)alloc(512 * 4);
    float* stbuf = (float*)alloc(512 * 4);
    float* cvec = (float*)alloc(256 * 4);
    u16* Wp = (u16*)alloc(256 * 256 * 2);
    int* bsum = (int*)alloc(1024 * 4);
    size_t offR = off;
    // conv-phase view of region R
    u16* Q = (u16*)(ws + offR);
    size_t convR = ((size_t)N * 64 * 2 + 255) & ~(size_t)255;
    // set2set-phase view of region R
    size_t o2 = offR;
    auto alloc2 = [&](size_t bytes) -> void* {
        void* p = ws + o2;
        o2 += (bytes + 255) & ~(size_t)255;
        return p;
    };
    u16* Wcat = (u16*)alloc2((size_t)1024 * 768 * 2);
    float* bcat = (float*)alloc2(1024 * 4);
    u16* qsh = (u16*)alloc2((size_t)G * 768 * 2);
    float* gates = (float*)alloc2((size_t)G * 1024 * 4);
    float* hsb = (float*)alloc2((size_t)G * 256 * 4);
    float* csb = (float*)alloc2((size_t)G * 256 * 4);
    size_t s2sR = o2 - offR;
    size_t need = offR + (convR > s2sR ? convR : s2sR);

    if (need > ws_size) {
        k_diagf<<<(G + 255) / 256, 256, 0, stream>>>((float*)d_out, G, 12345.0f);
        return;
    }

    // embed
    k_embed<<<N, 256, 0, stream>>>(x, atom_emb, X, N);
    // CSR build, in place in rp
    k_zero_int<<<(N + 255) / 256, 256, 0, stream>>>(rp, N);
    k_count<<<(E + 255) / 256, 256, 0, stream>>>(tgtp, rp, E);
    int nb1 = (N + 1023) / 1024;
    k_scan1<<<nb1, 256, 0, stream>>>(rp, bsum, N);
    k_scan2<<<1, 256, 0, stream>>>(bsum, nb1);
    k_scan3<<<(N + 255) / 256, 256, 0, stream>>>(rp, bsum, N);
    k_fill<<<(E + 255) / 256, 256, 0, stream>>>(srcp, tgtp, rp, esrc, E);

    int gipb = N / 64;
    int ccb = (N * 16 + 255) / 256;

    // conv1 (W1 -> fp16 Wp)
    k_cvtW<<<256, 256, 0, stream>>>(W1, Wp, 65536);
    k_gemm_ip<<<gipb, 256, 0, stream>>>(X, Wp, nullptr, N);
    k_zero_f32<<<2, 256, 0, stream>>>(stats, 512);
    for (int q = 0; q < 4; ++q) {
        k_copycol<<<ccb, 256, 0, stream>>>(X, Q, q, N);
        k_aggq<true><<<1024, 256, 0, stream>>>(Q, rp, esrc, b1, X, stats, q, N);
    }
    k_bnparam<<<1, 256, 0, stream>>>(stats, gamma, beta, stbuf, N);

    // conv2 (bn folded into Wp/cvec)
    k_fold<<<256, 256, 0, stream>>>(W2, stbuf, Wp, cvec);
    k_gemm_ip<<<gipb, 256, 0, stream>>>(X, Wp, cvec, N);
    k_zero_f32<<<2, 256, 0, stream>>>(stats, 512);
    for (int q = 0; q < 4; ++q) {
        k_copycol<<<ccb, 256, 0, stream>>>(X, Q, q, N);
        k_aggq<true><<<1024, 256, 0, stream>>>(Q, rp, esrc, b2, X, stats, q, N);
    }
    k_bnparam<<<1, 256, 0, stream>>>(stats, gamma, beta, stbuf, N);

    // conv3 (bn folded), no relu/stats
    k_fold<<<256, 256, 0, stream>>>(W3, stbuf, Wp, cvec);
    k_gemm_ip<<<gipb, 256, 0, stream>>>(X, Wp, cvec, N);
    for (int q = 0; q < 4; ++q) {
        k_copycol<<<ccb, 256, 0, stream>>>(X, Q, q, N);
        k_aggq<false><<<1024, 256, 0, stream>>>(Q, rp, esrc, b3, X, nullptr, q, N);
    }
    // h3 now in X

    // set2set
    k_wcat<<<1024, 256, 0, stream>>>(Wi, Wh, bi, bh, Wcat, bcat);
    k_zero_u16<<<(G * 768 + 255) / 256, 256, 0, stream>>>(qsh, G * 768);
    k_zero_f32<<<(G * 256 + 255) / 256, 256, 0, stream>>>(csb, G * 256);
    dim3 ggates(G / 128, 8);
    for (int s = 0; s < 4; ++s) {
        k_gemmf<<<ggates, 256, 0, stream>>>(qsh, Wcat, bcat, gates, G, 768, 1024);
        k_lstm<<<(G * 256 + 255) / 256, 256, 0, stream>>>(gates, csb, hsb, qsh, G);
        k_attn<<<G, 256, 0, stream>>>(X, hsb, batch, qsh, N, G);
    }
    k_final<<<G, 128, 0, stream>>>(qsh, l1W, l1b, l2W, l2b, (float*)d_out, G);
}